// Round 3
// baseline (803.162 us; speedup 1.0000x reference)
//
#include <hip/hip_runtime.h>
#include <hip/hip_bf16.h>

// GPT-2 block, B=2 S=4096 D=768 H=12 HD=64 INNER=3072. fp32 I/O, bf16 MFMA internals.
// Pipeline: transpose+cast weights -> LN1 -> GEMM qkv -> transpose V -> flash attn
//        -> GEMM cproj (+fp32 residual -> d_out) -> LN2 -> GEMM fc (+gelu) -> GEMM fcproj (+residual)
// ws: 38,535,168 bf16 elements = 77.1 MB. h (post-attn residual) lives in d_out (fp32).

#define S_     4096
#define D_     768
#define H_     12
#define HD_    64
#define NB_    2
#define M_     (NB_*S_)    // 8192 rows
#define QKV_   (3*D_)      // 2304
#define INNER_ 3072

typedef unsigned short u16;
typedef __attribute__((ext_vector_type(4))) float f32x4;
typedef __attribute__((ext_vector_type(8))) short s16x8;

__device__ __forceinline__ float bf2f(u16 h) {
    union { unsigned int u; float f; } c; c.u = ((unsigned int)h) << 16; return c.f;
}
__device__ __forceinline__ u16 f2bf(float f) {
    union { float f; unsigned int u; } c; c.f = f;
    return (u16)((c.u + 0x7fffu + ((c.u >> 16) & 1u)) >> 16);  // RNE
}
__device__ __forceinline__ void storev(u16* p, float v) { *p = f2bf(v); }
__device__ __forceinline__ void storev(float* p, float v) { *p = v; }

// async global->LDS, 16B per lane; LDS dest is wave-uniform base (+lane*16 implied)
__device__ __forceinline__ void gload_lds16(const u16* g, u16* l) {
    __builtin_amdgcn_global_load_lds((const __attribute__((address_space(1))) void*)g,
                                     (__attribute__((address_space(3))) void*)l, 16, 0, 0);
}

// ---------------- transpose 32x32 tiles; fp32->bf16 (weights) or bf16->bf16 (V) ----------------
template <typename IT>
__global__ __launch_bounds__(256) void transpose_kernel(const IT* __restrict__ in,
                                                        u16* __restrict__ out,
                                                        int ld_in, int ld_out) {
    __shared__ u16 tile[32][33];
    const int c0 = blockIdx.x * 32, r0 = blockIdx.y * 32;
    const int tx = threadIdx.x & 31, ty = threadIdx.x >> 5;  // ty 0..7
#pragma unroll
    for (int i = 0; i < 32; i += 8) {
        IT v = in[(size_t)(r0 + ty + i) * ld_in + c0 + tx];
        u16 bv;
        if constexpr (sizeof(IT) == 4) bv = f2bf((float)v); else bv = (u16)v;
        tile[ty + i][tx] = bv;
    }
    __syncthreads();
#pragma unroll
    for (int i = 0; i < 32; i += 8)
        out[(size_t)(c0 + ty + i) * ld_out + r0 + tx] = tile[tx][ty + i];
}

// ---------------- LayerNorm: one block per row of 768; fp32 in -> bf16 out ----------------
__global__ __launch_bounds__(256) void ln_row(const float* __restrict__ x, const float* __restrict__ g,
                                              const float* __restrict__ bb, u16* __restrict__ y) {
    const int row = blockIdx.x;
    const int tid = threadIdx.x;
    const float* xr = x + (size_t)row * D_;
    float v0 = xr[tid], v1 = xr[tid + 256], v2 = xr[tid + 512];
    float s = v0 + v1 + v2, s2 = v0 * v0 + v1 * v1 + v2 * v2;
#pragma unroll
    for (int d = 32; d >= 1; d >>= 1) { s += __shfl_xor(s, d, 64); s2 += __shfl_xor(s2, d, 64); }
    __shared__ float red[8];
    const int wave = tid >> 6, lane = tid & 63;
    if (lane == 0) { red[wave] = s; red[4 + wave] = s2; }
    __syncthreads();
    s = red[0] + red[1] + red[2] + red[3];
    s2 = red[4] + red[5] + red[6] + red[7];
    const float mu = s * (1.0f / D_);
    const float var = s2 * (1.0f / D_) - mu * mu;
    const float rstd = rsqrtf(var + 1e-5f);
    u16* yr = y + (size_t)row * D_;
    yr[tid]       = f2bf((v0 - mu) * rstd * g[tid]       + bb[tid]);
    yr[tid + 256] = f2bf((v1 - mu) * rstd * g[tid + 256] + bb[tid + 256]);
    yr[tid + 512] = f2bf((v2 - mu) * rstd * g[tid + 512] + bb[tid + 512]);
}

// ---------------- GEMM: C[M,N] = A[M,K] @ Bt[N,K]^T (+bias, epilogue) ----------------
// EPI: 0=none, 1=exact gelu, 2=add fp32 residual (res may alias C when OT=float)
// A,Bt bf16 in ws; bias/res fp32; OT = u16 (ws intermediate) or float (d_out)
// 128x128 tile, BK=32, 256 threads = 4 waves (2x2), each wave 64x64 via 4x4 mfma 16x16x32
template <int EPI, typename OT>
__global__ __launch_bounds__(256) void gemm_bt(const u16* __restrict__ A, const u16* __restrict__ Bt,
                                               const float* __restrict__ bias, const float* res,
                                               OT* C, int M, int N, int K) {
    __shared__ u16 As[128 * 32];
    __shared__ u16 Bs[128 * 32];
    const int tid = threadIdx.x;
    const int wave = tid >> 6, lane = tid & 63;
    const int m0 = blockIdx.y << 7, n0 = blockIdx.x << 7;
    const int fr = lane & 15, quad = lane >> 4;

    // staging: lane -> row wave*16 + lane/4 (+64), col (lane%4)*8
    const int srow = wave * 16 + (lane >> 2);
    const int scol = (lane & 3) * 8;
    const u16* ag0 = A + (size_t)(m0 + srow) * K + scol;
    const u16* ag1 = ag0 + (size_t)64 * K;
    const u16* bg0 = Bt + (size_t)(n0 + srow) * K + scol;
    const u16* bg1 = bg0 + (size_t)64 * K;
    u16* al0 = As + wave * 512;
    u16* al1 = As + 2048 + wave * 512;
    u16* bl0 = Bs + wave * 512;
    u16* bl1 = Bs + 2048 + wave * 512;

    const f32x4 fz = {0.f, 0.f, 0.f, 0.f};
    f32x4 acc[4][4];
#pragma unroll
    for (int i = 0; i < 4; i++)
#pragma unroll
        for (int j = 0; j < 4; j++) acc[i][j] = fz;

    const int wm = wave & 1, wn = wave >> 1;
    const u16* a_rd = As + (wm * 64 + fr) * 32 + quad * 8;
    const u16* b_rd = Bs + (wn * 64 + fr) * 32 + quad * 8;

    for (int k0 = 0; k0 < K; k0 += 32) {
        gload_lds16(ag0 + k0, al0);
        gload_lds16(ag1 + k0, al1);
        gload_lds16(bg0 + k0, bl0);
        gload_lds16(bg1 + k0, bl1);
        __syncthreads();
        s16x8 af[4], bfr[4];
#pragma unroll
        for (int t = 0; t < 4; t++) {
            af[t]  = *(const s16x8*)(a_rd + t * 16 * 32);
            bfr[t] = *(const s16x8*)(b_rd + t * 16 * 32);
        }
#pragma unroll
        for (int mt = 0; mt < 4; mt++)
#pragma unroll
            for (int nt = 0; nt < 4; nt++)
                acc[mt][nt] = __builtin_amdgcn_mfma_f32_16x16x32_bf16(af[mt], bfr[nt], acc[mt][nt], 0, 0, 0);
        __syncthreads();
    }

    // epilogue: C/D layout col=lane&15, row=quad*4+reg
    const int crow0 = m0 + wm * 64 + quad * 4;
    const int ccol0 = n0 + wn * 64 + fr;
#pragma unroll
    for (int nt = 0; nt < 4; nt++) {
        const int col = ccol0 + nt * 16;
        const float bv = bias[col];
#pragma unroll
        for (int mt = 0; mt < 4; mt++) {
#pragma unroll
            for (int r = 0; r < 4; r++) {
                const int row = crow0 + mt * 16 + r;
                float v = acc[mt][nt][r] + bv;
                if constexpr (EPI == 1) v = 0.5f * v * (1.0f + erff(v * 0.70710678118654752f));
                if constexpr (EPI == 2) v += res[(size_t)row * N + col];
                storev(&C[(size_t)row * N + col], v);
            }
        }
    }
}

// ---------------- flash attention (causal), one block per 128 q-rows per (b,h) ----------------
// qkv: [B*S, 2304] bf16 (q|k|v each 768 wide, head h at offset h*64). vt: [B, 768, S] bf16.
__global__ __launch_bounds__(256) void flash_attn(const u16* __restrict__ qkv, const u16* __restrict__ vt,
                                                  u16* __restrict__ ctx) {
    const int qb = (int)(gridDim.x - 1 - blockIdx.x);  // heavy (late) q-tiles first
    const int h = blockIdx.y, b = blockIdx.z;
    const int tid = threadIdx.x, wave = tid >> 6, lane = tid & 63;
    const int fr = lane & 15, quad = lane >> 4;
    const int q0 = qb << 7;

    __shared__ u16 Qs[128 * 64];
    __shared__ u16 Ks[64 * 64];
    __shared__ u16 Vs[64 * 64];      // transposed: Vs[hd][kv]
    __shared__ u16 Ps[4][32 * 64];   // per-wave P tile

    const u16* Qg  = qkv + (size_t)b * S_ * QKV_ + h * HD_;
    const u16* Kg  = Qg + D_;
    const u16* Vtg = vt + ((size_t)b * D_ + h * HD_) * S_;

    const int srow = lane >> 3;        // 0..7
    const int scol = (lane & 7) * 8;

    // stage Q tile [128][64]
#pragma unroll
    for (int i = 0; i < 4; i++)
        gload_lds16(Qg + (size_t)(q0 + i * 32 + wave * 8 + srow) * QKV_ + scol,
                    Qs + (i * 32 + wave * 8) * 64);

    const f32x4 fz = {0.f, 0.f, 0.f, 0.f};
    f32x4 o[2][4];
    float mrow[2][4], lrow[2][4];
#pragma unroll
    for (int mt = 0; mt < 2; mt++) {
#pragma unroll
        for (int nt = 0; nt < 4; nt++) o[mt][nt] = fz;
#pragma unroll
        for (int r = 0; r < 4; r++) { mrow[mt][r] = -1e30f; lrow[mt][r] = 0.f; }
    }

    const int ntiles = (q0 >> 6) + 2;  // kv tiles of 64 covering kv <= q0+127
    for (int t = 0; t < ntiles; t++) {
        const int k0 = t << 6;
        gload_lds16(Kg + (size_t)(k0 + wave * 8 + srow) * QKV_ + scol, Ks + wave * 8 * 64);
        gload_lds16(Kg + (size_t)(k0 + 32 + wave * 8 + srow) * QKV_ + scol, Ks + (32 + wave * 8) * 64);
        gload_lds16(Vtg + (size_t)(wave * 8 + srow) * S_ + k0 + scol, Vs + wave * 8 * 64);
        gload_lds16(Vtg + (size_t)(32 + wave * 8 + srow) * S_ + k0 + scol, Vs + (32 + wave * 8) * 64);
        __syncthreads();

        // scores: wave rows [wave*32, wave*32+32) x kv [k0, k0+64)
        f32x4 sc[2][4];
#pragma unroll
        for (int mt = 0; mt < 2; mt++)
#pragma unroll
            for (int nt = 0; nt < 4; nt++) sc[mt][nt] = fz;
#pragma unroll
        for (int kk = 0; kk < 2; kk++) {
            s16x8 qf[2], kf[4];
#pragma unroll
            for (int mt = 0; mt < 2; mt++)
                qf[mt] = *(const s16x8*)(Qs + (wave * 32 + mt * 16 + fr) * 64 + kk * 32 + quad * 8);
#pragma unroll
            for (int nt = 0; nt < 4; nt++)
                kf[nt] = *(const s16x8*)(Ks + (nt * 16 + fr) * 64 + kk * 32 + quad * 8);
#pragma unroll
            for (int mt = 0; mt < 2; mt++)
#pragma unroll
                for (int nt = 0; nt < 4; nt++)
                    sc[mt][nt] = __builtin_amdgcn_mfma_f32_16x16x32_bf16(qf[mt], kf[nt], sc[mt][nt], 0, 0, 0);
        }

        // online softmax; C-layout: col=k0+nt*16+fr, row=q0+wave*32+mt*16+quad*4+r
#pragma unroll
        for (int mt = 0; mt < 2; mt++) {
#pragma unroll
            for (int r = 0; r < 4; r++) {
                const int grow = q0 + wave * 32 + mt * 16 + quad * 4 + r;
                float s0 = sc[mt][0][r] * 0.125f; if (k0 +  0 + fr > grow) s0 = -1e30f;
                float s1 = sc[mt][1][r] * 0.125f; if (k0 + 16 + fr > grow) s1 = -1e30f;
                float s2 = sc[mt][2][r] * 0.125f; if (k0 + 32 + fr > grow) s2 = -1e30f;
                float s3 = sc[mt][3][r] * 0.125f; if (k0 + 48 + fr > grow) s3 = -1e30f;
                float mx = fmaxf(fmaxf(s0, s1), fmaxf(s2, s3));
#pragma unroll
                for (int d = 1; d < 16; d <<= 1) mx = fmaxf(mx, __shfl_xor(mx, d, 16));
                const float mn = fmaxf(mrow[mt][r], mx);
                const float alpha = __expf(mrow[mt][r] - mn);
                mrow[mt][r] = mn;
                s0 = __expf(s0 - mn); s1 = __expf(s1 - mn);
                s2 = __expf(s2 - mn); s3 = __expf(s3 - mn);
                float rs = s0 + s1 + s2 + s3;
#pragma unroll
                for (int d = 1; d < 16; d <<= 1) rs += __shfl_xor(rs, d, 16);
                lrow[mt][r] = lrow[mt][r] * alpha + rs;
#pragma unroll
                for (int nt = 0; nt < 4; nt++) o[mt][nt][r] *= alpha;
                u16* prow = Ps[wave] + (mt * 16 + quad * 4 + r) * 64 + fr;
                prow[0] = f2bf(s0); prow[16] = f2bf(s1); prow[32] = f2bf(s2); prow[48] = f2bf(s3);
            }
        }

        // O += P @ V  (P in A-layout from LDS, V transposed so B-operand reads contiguous)
#pragma unroll
        for (int kk = 0; kk < 2; kk++) {
            s16x8 pf[2], vf[4];
#pragma unroll
            for (int mt = 0; mt < 2; mt++)
                pf[mt] = *(const s16x8*)(Ps[wave] + (mt * 16 + fr) * 64 + kk * 32 + quad * 8);
#pragma unroll
            for (int nt = 0; nt < 4; nt++)
                vf[nt] = *(const s16x8*)(Vs + (nt * 16 + fr) * 64 + kk * 32 + quad * 8);
#pragma unroll
            for (int mt = 0; mt < 2; mt++)
#pragma unroll
                for (int nt = 0; nt < 4; nt++)
                    o[mt][nt] = __builtin_amdgcn_mfma_f32_16x16x32_bf16(pf[mt], vf[nt], o[mt][nt], 0, 0, 0);
        }
        __syncthreads();
    }

    // normalize and write ctx [B*S, 768] bf16 (merged heads)
#pragma unroll
    for (int mt = 0; mt < 2; mt++) {
#pragma unroll
        for (int r = 0; r < 4; r++) {
            const int grow = q0 + wave * 32 + mt * 16 + quad * 4 + r;
            const float inv = 1.0f / lrow[mt][r];
            u16* crow = ctx + ((size_t)b * S_ + grow) * D_ + h * HD_ + fr;
#pragma unroll
            for (int nt = 0; nt < 4; nt++)
                crow[nt * 16] = f2bf(o[mt][nt][r] * inv);
        }
    }
}

extern "C" void kernel_launch(void* const* d_in, const int* in_sizes, int n_in,
                              void* d_out, int out_size, void* d_ws, size_t ws_size,
                              hipStream_t stream) {
    const float* hid    = (const float*)d_in[0];
    // d_in[1] = attention_mask: fixed causal mask, applied analytically in flash_attn
    const float* ln1g   = (const float*)d_in[2];
    const float* ln1b   = (const float*)d_in[3];
    const float* w_attn = (const float*)d_in[4];
    const float* b_attn = (const float*)d_in[5];
    const float* w_cp   = (const float*)d_in[6];
    const float* b_cp   = (const float*)d_in[7];
    const float* ln2g   = (const float*)d_in[8];
    const float* ln2b   = (const float*)d_in[9];
    const float* w_fc   = (const float*)d_in[10];
    const float* b_fc   = (const float*)d_in[11];
    const float* w_fp   = (const float*)d_in[12];
    const float* b_fp   = (const float*)d_in[13];
    float* dout = (float*)d_out;

    // ws layout (bf16 elements), total 38,535,168 = 77.1 MB:
    u16* ws = (u16*)d_ws;
    u16* wTa  = ws; ws += (size_t)QKV_ * D_;     // w_attn^T   [2304,768]
    u16* wTc  = ws; ws += (size_t)D_ * D_;       // w_cproj^T  [768,768]
    u16* wTf  = ws; ws += (size_t)INNER_ * D_;   // w_fc^T     [3072,768]
    u16* wTp  = ws; ws += (size_t)D_ * INNER_;   // w_fcproj^T [768,3072]
    u16* xln  = ws; ws += (size_t)M_ * D_;       // LN1 out -> (dead) -> ctx -> (dead) -> LN2 out
    u16* qkvb = ws; ws += (size_t)M_ * QKV_;     // qkv; act aliases qkvb+vtb (exactly M*INNER)
    u16* vtb  = ws; ws += (size_t)NB_ * D_ * S_; // V^T per batch [768,4096]
    u16* ctxb = xln;
    u16* yln  = xln;
    u16* act  = qkvb;   // M_*INNER_ = 25,165,824 == qkvb(18,874,368) + vtb(6,291,456)
    // h (post-attn residual, fp32) lives in d_out

    dim3 blk(256);
    transpose_kernel<float><<<dim3(QKV_ / 32, D_ / 32), blk, 0, stream>>>(w_attn, wTa, QKV_, D_);
    transpose_kernel<float><<<dim3(D_ / 32, D_ / 32), blk, 0, stream>>>(w_cp, wTc, D_, D_);
    transpose_kernel<float><<<dim3(INNER_ / 32, D_ / 32), blk, 0, stream>>>(w_fc, wTf, INNER_, D_);
    transpose_kernel<float><<<dim3(D_ / 32, INNER_ / 32), blk, 0, stream>>>(w_fp, wTp, D_, INNER_);

    ln_row<<<M_, blk, 0, stream>>>(hid, ln1g, ln1b, xln);
    gemm_bt<0, u16><<<dim3(QKV_ / 128, M_ / 128), blk, 0, stream>>>(xln, wTa, b_attn, nullptr, qkvb, M_, QKV_, D_);

    transpose_kernel<u16><<<dim3(D_ / 32, S_ / 32), blk, 0, stream>>>(qkvb + 2 * D_, vtb, QKV_, S_);
    transpose_kernel<u16><<<dim3(D_ / 32, S_ / 32), blk, 0, stream>>>(qkvb + (size_t)S_ * QKV_ + 2 * D_,
                                                                      vtb + (size_t)D_ * S_, QKV_, S_);
    flash_attn<<<dim3(S_ / 128, H_, NB_), blk, 0, stream>>>(qkvb, vtb, ctxb);

    gemm_bt<2, float><<<dim3(D_ / 128, M_ / 128), blk, 0, stream>>>(ctxb, wTc, b_cp, hid, dout, M_, D_, D_);
    ln_row<<<M_, blk, 0, stream>>>(dout, ln2g, ln2b, yln);
    gemm_bt<1, u16><<<dim3(INNER_ / 128, M_ / 128), blk, 0, stream>>>(yln, wTf, b_fc, nullptr, act, M_, INNER_, D_);
    gemm_bt<2, float><<<dim3(D_ / 128, M_ / 128), blk, 0, stream>>>(act, wTp, b_fp, dout, dout, M_, D_, INNER_);
}

// Round 4
// 726.726 us; speedup vs baseline: 1.1052x; 1.1052x over previous
//
#include <hip/hip_runtime.h>
#include <hip/hip_bf16.h>

// GPT-2 block, B=2 S=4096 D=768 H=12 HD=64 INNER=3072. fp32 I/O, bf16 MFMA internals.
// R4: flash_attn rewritten — k-permuted P/V layout (conflict-free ds_write_b64),
// row-sums via ones-MFMA, exp2-domain softmax, packed bf16 cvt, Q-frag hoist,
// Ps aliased onto Qs (LDS 48->32KB, 3->4 blocks/CU).

#define S_     4096
#define D_     768
#define H_     12
#define HD_    64
#define NB_    2
#define M_     (NB_*S_)    // 8192 rows
#define QKV_   (3*D_)      // 2304
#define INNER_ 3072

typedef unsigned short u16;
typedef __attribute__((ext_vector_type(4))) float f32x4;
typedef __attribute__((ext_vector_type(8))) short s16x8;

__device__ __forceinline__ float bf2f(u16 h) {
    union { unsigned int u; float f; } c; c.u = ((unsigned int)h) << 16; return c.f;
}
__device__ __forceinline__ u16 f2bf(float f) {
    union { float f; unsigned int u; } c; c.f = f;
    return (u16)((c.u + 0x7fffu + ((c.u >> 16) & 1u)) >> 16);  // RNE
}
__device__ __forceinline__ void storev(u16* p, float v) { *p = f2bf(v); }
__device__ __forceinline__ void storev(float* p, float v) { *p = v; }

__device__ __forceinline__ float fexp2(float x) {
#if __has_builtin(__builtin_amdgcn_exp2f)
    return __builtin_amdgcn_exp2f(x);
#else
    return __expf(x * 0.69314718056f);
#endif
}
__device__ __forceinline__ unsigned int packbf(float a, float b) {
    union { __hip_bfloat162 h; unsigned int u; } c;
    c.h = __float22bfloat162_rn(float2{a, b});
    return c.u;
}

// async global->LDS, 16B per lane; LDS dest is wave-uniform base (+lane*16 implied)
__device__ __forceinline__ void gload_lds16(const u16* g, u16* l) {
    __builtin_amdgcn_global_load_lds((const __attribute__((address_space(1))) void*)g,
                                     (__attribute__((address_space(3))) void*)l, 16, 0, 0);
}

// ---------------- transpose 32x32 tiles; fp32->bf16 (weights) or bf16->bf16 (V) ----------------
// PERM: permute output column within each 64-chunk: p = (c%16)*4 + (c/16)%4  (flash k-permutation)
template <typename IT, bool PERM>
__global__ __launch_bounds__(256) void transpose_kernel(const IT* __restrict__ in,
                                                        u16* __restrict__ out,
                                                        int ld_in, int ld_out) {
    __shared__ u16 tile[32][33];
    const int c0 = blockIdx.x * 32, r0 = blockIdx.y * 32;
    const int tx = threadIdx.x & 31, ty = threadIdx.x >> 5;  // ty 0..7
#pragma unroll
    for (int i = 0; i < 32; i += 8) {
        IT v = in[(size_t)(r0 + ty + i) * ld_in + c0 + tx];
        u16 bv;
        if constexpr (sizeof(IT) == 4) bv = f2bf((float)v); else bv = (u16)v;
        tile[ty + i][tx] = bv;
    }
    __syncthreads();
    int oc = r0 + tx;
    if constexpr (PERM) oc = (oc & ~63) | (((oc & 15) << 2) | ((oc >> 4) & 3));
#pragma unroll
    for (int i = 0; i < 32; i += 8)
        out[(size_t)(c0 + ty + i) * ld_out + oc] = tile[tx][ty + i];
}

// ---------------- LayerNorm: one block per row of 768; fp32 in -> bf16 out ----------------
__global__ __launch_bounds__(256) void ln_row(const float* __restrict__ x, const float* __restrict__ g,
                                              const float* __restrict__ bb, u16* __restrict__ y) {
    const int row = blockIdx.x;
    const int tid = threadIdx.x;
    const float* xr = x + (size_t)row * D_;
    float v0 = xr[tid], v1 = xr[tid + 256], v2 = xr[tid + 512];
    float s = v0 + v1 + v2, s2 = v0 * v0 + v1 * v1 + v2 * v2;
#pragma unroll
    for (int d = 32; d >= 1; d >>= 1) { s += __shfl_xor(s, d, 64); s2 += __shfl_xor(s2, d, 64); }
    __shared__ float red[8];
    const int wave = tid >> 6, lane = tid & 63;
    if (lane == 0) { red[wave] = s; red[4 + wave] = s2; }
    __syncthreads();
    s = red[0] + red[1] + red[2] + red[3];
    s2 = red[4] + red[5] + red[6] + red[7];
    const float mu = s * (1.0f / D_);
    const float var = s2 * (1.0f / D_) - mu * mu;
    const float rstd = rsqrtf(var + 1e-5f);
    u16* yr = y + (size_t)row * D_;
    yr[tid]       = f2bf((v0 - mu) * rstd * g[tid]       + bb[tid]);
    yr[tid + 256] = f2bf((v1 - mu) * rstd * g[tid + 256] + bb[tid + 256]);
    yr[tid + 512] = f2bf((v2 - mu) * rstd * g[tid + 512] + bb[tid + 512]);
}

// ---------------- GEMM: C[M,N] = A[M,K] @ Bt[N,K]^T (+bias, epilogue) ----------------
template <int EPI, typename OT>
__global__ __launch_bounds__(256) void gemm_bt(const u16* __restrict__ A, const u16* __restrict__ Bt,
                                               const float* __restrict__ bias, const float* res,
                                               OT* C, int M, int N, int K) {
    __shared__ u16 As[128 * 32];
    __shared__ u16 Bs[128 * 32];
    const int tid = threadIdx.x;
    const int wave = tid >> 6, lane = tid & 63;
    const int m0 = blockIdx.y << 7, n0 = blockIdx.x << 7;
    const int fr = lane & 15, quad = lane >> 4;

    const int srow = wave * 16 + (lane >> 2);
    const int scol = (lane & 3) * 8;
    const u16* ag0 = A + (size_t)(m0 + srow) * K + scol;
    const u16* ag1 = ag0 + (size_t)64 * K;
    const u16* bg0 = Bt + (size_t)(n0 + srow) * K + scol;
    const u16* bg1 = bg0 + (size_t)64 * K;
    u16* al0 = As + wave * 512;
    u16* al1 = As + 2048 + wave * 512;
    u16* bl0 = Bs + wave * 512;
    u16* bl1 = Bs + 2048 + wave * 512;

    const f32x4 fz = {0.f, 0.f, 0.f, 0.f};
    f32x4 acc[4][4];
#pragma unroll
    for (int i = 0; i < 4; i++)
#pragma unroll
        for (int j = 0; j < 4; j++) acc[i][j] = fz;

    const int wm = wave & 1, wn = wave >> 1;
    const u16* a_rd = As + (wm * 64 + fr) * 32 + quad * 8;
    const u16* b_rd = Bs + (wn * 64 + fr) * 32 + quad * 8;

    for (int k0 = 0; k0 < K; k0 += 32) {
        gload_lds16(ag0 + k0, al0);
        gload_lds16(ag1 + k0, al1);
        gload_lds16(bg0 + k0, bl0);
        gload_lds16(bg1 + k0, bl1);
        __syncthreads();
        s16x8 af[4], bfr[4];
#pragma unroll
        for (int t = 0; t < 4; t++) {
            af[t]  = *(const s16x8*)(a_rd + t * 16 * 32);
            bfr[t] = *(const s16x8*)(b_rd + t * 16 * 32);
        }
#pragma unroll
        for (int mt = 0; mt < 4; mt++)
#pragma unroll
            for (int nt = 0; nt < 4; nt++)
                acc[mt][nt] = __builtin_amdgcn_mfma_f32_16x16x32_bf16(af[mt], bfr[nt], acc[mt][nt], 0, 0, 0);
        __syncthreads();
    }

    const int crow0 = m0 + wm * 64 + quad * 4;
    const int ccol0 = n0 + wn * 64 + fr;
#pragma unroll
    for (int nt = 0; nt < 4; nt++) {
        const int col = ccol0 + nt * 16;
        const float bv = bias[col];
#pragma unroll
        for (int mt = 0; mt < 4; mt++) {
#pragma unroll
            for (int r = 0; r < 4; r++) {
                const int row = crow0 + mt * 16 + r;
                float v = acc[mt][nt][r] + bv;
                if constexpr (EPI == 1) v = 0.5f * v * (1.0f + erff(v * 0.70710678118654752f));
                if constexpr (EPI == 2) v += res[(size_t)row * N + col];
                storev(&C[(size_t)row * N + col], v);
            }
        }
    }
}

// ---------------- flash attention (causal), one block per 128 q-rows per (b,h) ----------------
// qkv: [B*S, 2304] bf16. vt: [B, 768, S] bf16 with kv k-permuted within 64-chunks.
// P LDS layout uses same k-permutation -> lane's 4 P values contiguous (ds_write_b64, no conflicts).
// Row-sum l computed via MFMA against all-ones B fragment. Softmax in exp2 domain.
#define SCALE_ 0.1803368801111f  /* 0.125 * log2(e) */
__global__ __launch_bounds__(256, 4) void flash_attn(const u16* __restrict__ qkv, const u16* __restrict__ vt,
                                                     u16* __restrict__ ctx) {
    const int qb = (int)(gridDim.x - 1 - blockIdx.x);  // heavy (late) q-tiles first
    const int h = blockIdx.y, b = blockIdx.z;
    const int tid = threadIdx.x, wave = tid >> 6, lane = tid & 63;
    const int fr = lane & 15, quad = lane >> 4;
    const int q0 = qb << 7;

    __shared__ u16 Qs[128 * 64];     // rows [wave*32, wave*32+32) reused as this wave's P tile
    __shared__ u16 Ks[64 * 64];
    __shared__ u16 Vs[64 * 64];      // Vs[hd][p] with p = k-permuted kv
    u16* Ps = Qs + wave * (32 * 64); // wave-private; safe: wave only reads its own Q band

    const u16* Qg  = qkv + (size_t)b * S_ * QKV_ + h * HD_;
    const u16* Kg  = Qg + D_;
    const u16* Vtg = vt + ((size_t)b * D_ + h * HD_) * S_;

    const int srow = lane >> 3;        // 0..7
    const int scol = (lane & 7) * 8;

    // stage Q tile [128][64]
#pragma unroll
    for (int i = 0; i < 4; i++)
        gload_lds16(Qg + (size_t)(q0 + i * 32 + wave * 8 + srow) * QKV_ + scol,
                    Qs + (i * 32 + wave * 8) * 64);
    __syncthreads();

    // hoist loop-invariant Q fragments (A-layout: m=fr, k=kk*32+quad*8+j)
    s16x8 qf[2][2];
#pragma unroll
    for (int mt = 0; mt < 2; mt++)
#pragma unroll
        for (int kk = 0; kk < 2; kk++)
            qf[mt][kk] = *(const s16x8*)(Qs + (wave * 32 + mt * 16 + fr) * 64 + kk * 32 + quad * 8);

    const f32x4 fz = {0.f, 0.f, 0.f, 0.f};
    f32x4 o[2][4];
    f32x4 ls[2];
    float mrow[2][4];
#pragma unroll
    for (int mt = 0; mt < 2; mt++) {
        ls[mt] = fz;
#pragma unroll
        for (int nt = 0; nt < 4; nt++) o[mt][nt] = fz;
#pragma unroll
        for (int r = 0; r < 4; r++) mrow[mt][r] = -1e30f;
    }
    s16x8 ones;
#pragma unroll
    for (int j = 0; j < 8; j++) ones[j] = (short)0x3F80;  // 1.0 bf16

    const int ntiles = 2 * qb + 2;
    for (int t = 0; t < ntiles; t++) {
        const int k0 = t << 6;
        gload_lds16(Kg + (size_t)(k0 + wave * 8 + srow) * QKV_ + scol, Ks + wave * 8 * 64);
        gload_lds16(Kg + (size_t)(k0 + 32 + wave * 8 + srow) * QKV_ + scol, Ks + (32 + wave * 8) * 64);
        gload_lds16(Vtg + (size_t)(wave * 8 + srow) * S_ + k0 + scol, Vs + wave * 8 * 64);
        gload_lds16(Vtg + (size_t)(32 + wave * 8 + srow) * S_ + k0 + scol, Vs + (32 + wave * 8) * 64);
        __syncthreads();

        const bool active = (k0 <= q0 + wave * 32 + 31);
        if (active) {
            // scores: wave rows [wave*32, +32) x kv [k0, k0+64)
            f32x4 sc[2][4];
#pragma unroll
            for (int mt = 0; mt < 2; mt++)
#pragma unroll
                for (int nt = 0; nt < 4; nt++) sc[mt][nt] = fz;
#pragma unroll
            for (int kk = 0; kk < 2; kk++) {
                s16x8 kf[4];
#pragma unroll
                for (int nt = 0; nt < 4; nt++)
                    kf[nt] = *(const s16x8*)(Ks + (nt * 16 + fr) * 64 + kk * 32 + quad * 8);
#pragma unroll
                for (int mt = 0; mt < 2; mt++)
#pragma unroll
                    for (int nt = 0; nt < 4; nt++)
                        sc[mt][nt] = __builtin_amdgcn_mfma_f32_16x16x32_bf16(qf[mt][kk], kf[nt], sc[mt][nt], 0, 0, 0);
            }

            const bool fast = (k0 + 63 <= q0 + wave * 32);  // no masking needed for this wave
            // online softmax (exp2 domain); C-layout: col=k0+nt*16+fr, row=q0+wave*32+mt*16+quad*4+r
#pragma unroll
            for (int mt = 0; mt < 2; mt++) {
#pragma unroll
                for (int r = 0; r < 4; r++) {
                    const int grow = q0 + wave * 32 + mt * 16 + quad * 4 + r;
                    float s0 = sc[mt][0][r] * SCALE_;
                    float s1 = sc[mt][1][r] * SCALE_;
                    float s2 = sc[mt][2][r] * SCALE_;
                    float s3 = sc[mt][3][r] * SCALE_;
                    if (!fast) {
                        const int lim = grow - k0;
                        if (fr      > lim) s0 = -1e30f;
                        if (fr + 16 > lim) s1 = -1e30f;
                        if (fr + 32 > lim) s2 = -1e30f;
                        if (fr + 48 > lim) s3 = -1e30f;
                    }
                    float mx = fmaxf(fmaxf(s0, s1), fmaxf(s2, s3));
#pragma unroll
                    for (int d = 1; d < 16; d <<= 1) mx = fmaxf(mx, __shfl_xor(mx, d, 16));
                    const float mn = fmaxf(mrow[mt][r], mx);
                    const float alpha = fexp2(mrow[mt][r] - mn);
                    mrow[mt][r] = mn;
                    s0 = fexp2(s0 - mn); s1 = fexp2(s1 - mn);
                    s2 = fexp2(s2 - mn); s3 = fexp2(s3 - mn);
                    ls[mt][r] *= alpha;
#pragma unroll
                    for (int nt = 0; nt < 4; nt++) o[mt][nt][r] *= alpha;
                    // permuted P: values for cols fr+16t land at p = fr*4 + t (contiguous)
                    *(uint2*)(Ps + (mt * 16 + quad * 4 + r) * 64 + fr * 4) =
                        make_uint2(packbf(s0, s1), packbf(s2, s3));
                }
            }

            // P fragments (A-layout over permuted k) — same-wave DS ordering makes this safe
            s16x8 pf[2][2];
#pragma unroll
            for (int mt = 0; mt < 2; mt++)
#pragma unroll
                for (int kk = 0; kk < 2; kk++)
                    pf[mt][kk] = *(const s16x8*)(Ps + (mt * 16 + fr) * 64 + kk * 32 + quad * 8);

            // l += row-sum(P) via ones-MFMA (fp32, replicated across cols)
#pragma unroll
            for (int mt = 0; mt < 2; mt++) {
                ls[mt] = __builtin_amdgcn_mfma_f32_16x16x32_bf16(pf[mt][0], ones, ls[mt], 0, 0, 0);
                ls[mt] = __builtin_amdgcn_mfma_f32_16x16x32_bf16(pf[mt][1], ones, ls[mt], 0, 0, 0);
            }

            // O += P @ V (both sides in the same permuted-k order)
#pragma unroll
            for (int kk = 0; kk < 2; kk++) {
                s16x8 vf[4];
#pragma unroll
                for (int nt = 0; nt < 4; nt++)
                    vf[nt] = *(const s16x8*)(Vs + (nt * 16 + fr) * 64 + kk * 32 + quad * 8);
#pragma unroll
                for (int mt = 0; mt < 2; mt++)
#pragma unroll
                    for (int nt = 0; nt < 4; nt++)
                        o[mt][nt] = __builtin_amdgcn_mfma_f32_16x16x32_bf16(pf[mt][kk], vf[nt], o[mt][nt], 0, 0, 0);
            }
        }
        __syncthreads();
    }

    // normalize and write ctx [B*S, 768] bf16 (merged heads)
#pragma unroll
    for (int mt = 0; mt < 2; mt++) {
#pragma unroll
        for (int r = 0; r < 4; r++) {
            const int grow = q0 + wave * 32 + mt * 16 + quad * 4 + r;
            const float inv = 1.0f / ls[mt][r];
            u16* crow = ctx + ((size_t)b * S_ + grow) * D_ + h * HD_ + fr;
#pragma unroll
            for (int nt = 0; nt < 4; nt++)
                crow[nt * 16] = f2bf(o[mt][nt][r] * inv);
        }
    }
}

extern "C" void kernel_launch(void* const* d_in, const int* in_sizes, int n_in,
                              void* d_out, int out_size, void* d_ws, size_t ws_size,
                              hipStream_t stream) {
    const float* hid    = (const float*)d_in[0];
    // d_in[1] = attention_mask: fixed causal mask, applied analytically in flash_attn
    const float* ln1g   = (const float*)d_in[2];
    const float* ln1b   = (const float*)d_in[3];
    const float* w_attn = (const float*)d_in[4];
    const float* b_attn = (const float*)d_in[5];
    const float* w_cp   = (const float*)d_in[6];
    const float* b_cp   = (const float*)d_in[7];
    const float* ln2g   = (const float*)d_in[8];
    const float* ln2b   = (const float*)d_in[9];
    const float* w_fc   = (const float*)d_in[10];
    const float* b_fc   = (const float*)d_in[11];
    const float* w_fp   = (const float*)d_in[12];
    const float* b_fp   = (const float*)d_in[13];
    float* dout = (float*)d_out;

    // ws layout (bf16 elements), total 38,535,168 = 77.1 MB:
    u16* ws = (u16*)d_ws;
    u16* wTa  = ws; ws += (size_t)QKV_ * D_;     // w_attn^T   [2304,768]
    u16* wTc  = ws; ws += (size_t)D_ * D_;       // w_cproj^T  [768,768]
    u16* wTf  = ws; ws += (size_t)INNER_ * D_;   // w_fc^T     [3072,768]
    u16* wTp  = ws; ws += (size_t)D_ * INNER_;   // w_fcproj^T [768,3072]
    u16* xln  = ws; ws += (size_t)M_ * D_;       // LN1 out -> ctx -> LN2 out
    u16* qkvb = ws; ws += (size_t)M_ * QKV_;     // qkv; act aliases qkvb+vtb
    u16* vtb  = ws; ws += (size_t)NB_ * D_ * S_; // V^T per batch [768,4096], kv k-permuted
    u16* ctxb = xln;
    u16* yln  = xln;
    u16* act  = qkvb;   // M_*INNER_ == qkvb+vtb sizes
    // h (post-attn residual, fp32) lives in d_out

    dim3 blk(256);
    transpose_kernel<float, false><<<dim3(QKV_ / 32, D_ / 32), blk, 0, stream>>>(w_attn, wTa, QKV_, D_);
    transpose_kernel<float, false><<<dim3(D_ / 32, D_ / 32), blk, 0, stream>>>(w_cp, wTc, D_, D_);
    transpose_kernel<float, false><<<dim3(INNER_ / 32, D_ / 32), blk, 0, stream>>>(w_fc, wTf, INNER_, D_);
    transpose_kernel<float, false><<<dim3(D_ / 32, INNER_ / 32), blk, 0, stream>>>(w_fp, wTp, D_, INNER_);

    ln_row<<<M_, blk, 0, stream>>>(hid, ln1g, ln1b, xln);
    gemm_bt<0, u16><<<dim3(QKV_ / 128, M_ / 128), blk, 0, stream>>>(xln, wTa, b_attn, nullptr, qkvb, M_, QKV_, D_);

    transpose_kernel<u16, true><<<dim3(D_ / 32, S_ / 32), blk, 0, stream>>>(qkvb + 2 * D_, vtb, QKV_, S_);
    transpose_kernel<u16, true><<<dim3(D_ / 32, S_ / 32), blk, 0, stream>>>(qkvb + (size_t)S_ * QKV_ + 2 * D_,
                                                                            vtb + (size_t)D_ * S_, QKV_, S_);
    flash_attn<<<dim3(S_ / 128, H_, NB_), blk, 0, stream>>>(qkvb, vtb, ctxb);

    gemm_bt<2, float><<<dim3(D_ / 128, M_ / 128), blk, 0, stream>>>(ctxb, wTc, b_cp, hid, dout, M_, D_, D_);
    ln_row<<<M_, blk, 0, stream>>>(dout, ln2g, ln2b, yln);
    gemm_bt<1, u16><<<dim3(INNER_ / 128, M_ / 128), blk, 0, stream>>>(yln, wTf, b_fc, nullptr, act, M_, INNER_, D_);
    gemm_bt<2, float><<<dim3(D_ / 128, M_ / 128), blk, 0, stream>>>(act, wTp, b_fp, dout, dout, M_, D_, INNER_);
}